// Round 6
// baseline (1201.246 us; speedup 1.0000x reference)
//
#include <hip/hip_runtime.h>
#include <hip/hip_fp16.h>
#include <hip/hip_cooperative_groups.h>

#define DIM 128
#define TSH 8
#define TSZ 256     // dst-tile size (nodes per tile)
#define EBLK 3200   // edges per block chunk (ceil(1.6M/500))
#define NB 512      // cooperative grid size (2 blocks/CU on 256 CUs)
#define SCH 2048    // scan chunk (1024 thr x 2)

typedef _Float16 half8_t __attribute__((ext_vector_type(8)));
typedef float f32x4 __attribute__((ext_vector_type(4)));
typedef float f32x4v __attribute__((ext_vector_type(4)));

namespace cg = cooperative_groups;

// ws: hn f16[n*128] (25.6MB) | Wf f16[16384] | rs i32[n+1 pad] |
//     gh i32[nt*neb] (~0.8MB) | bsum i32[256] | tbuf u32[ne] | ebuf i32[ne]
// Assumptions (n=100000, ne=1.6M): nt=391<=512, neb=500<=NB-2, nsc=96<=256.

struct SM {
    int ps[256];
    int gbl[256];
    int wsum[16];
    union {
        int h1[512];
        struct {
            int hD[512];
            int cur[512];
            unsigned sval[EBLK];
            unsigned short skey[EBLK];
        } p3;
        struct {
            int hist[256];
            int cur[256];
        } p4;
    } u;
};

// ---- Phase 1: per-block LDS histogram of dst-tile key -> gh[key*neb+blk].
// Blocks [neb, neb+2): Wf table:
// Wf[((tile*4+kk)*64+lane)*8+j] = W[tile*16+(lane&15)][kk*32+(lane>>4)*8+j]
__device__ void phase_hist(SM& s, int blk, int t,
                           const int* __restrict__ dst, int* __restrict__ gh,
                           int ne, int neb, int nt,
                           const float* __restrict__ W,
                           _Float16* __restrict__ Wf) {
    if (blk >= neb) {
        int ii = blk - neb;
        if (ii < 2) {
            int idx = ii * 1024 + t;  // 0..2047
            int tile = idx >> 8, kk = (idx >> 6) & 3, lane = idx & 63;
            int nn = lane & 15, quad = lane >> 4;
            const float* wr = W + (tile * 16 + nn) * DIM + kk * 32 + quad * 8;
            _Float16* o = Wf + (size_t)idx * 8;
#pragma unroll
            for (int j = 0; j < 8; ++j) o[j] = (_Float16)wr[j];
        }
        return;
    }
    if (t < 512) s.u.h1[t] = 0;
    __syncthreads();
    int e0 = blk * EBLK;
    int e1 = e0 + EBLK; if (e1 > ne) e1 = ne;
    for (int i = e0 + t; i < e1; i += 1024)
        atomicAdd(&s.u.h1[dst[i] >> TSH], 1);
    __syncthreads();
    for (int k = t; k < nt; k += 1024) gh[k * neb + blk] = s.u.h1[k];
}

// ---- Phase 2: exclusive scan of gh in 2048-chunks; bsum[chunk] = raw total.
__device__ void phase_scan(SM& s, int blk, int t,
                           int* __restrict__ g, int* __restrict__ bsum, int M) {
    int base = blk * SCH + t * 2;
    int v0 = (base < M) ? g[base] : 0;
    int v1 = (base + 1 < M) ? g[base + 1] : 0;
    int s2 = v0 + v1;
    int lane = t & 63, wv = t >> 6;
    int x = s2;
#pragma unroll
    for (int off = 1; off < 64; off <<= 1) {
        int y = __shfl_up(x, off, 64);
        if (lane >= off) x += y;
    }
    if (lane == 63) s.wsum[wv] = x;
    __syncthreads();
    int woff = 0;
    for (int i = 0; i < wv; ++i) woff += s.wsum[i];
    int ex = woff + x - s2;
    if (base < M) g[base] = ex;
    if (base + 1 < M) g[base + 1] = ex + v0;
    if (t == 0) {
        int tt = 0;
#pragma unroll
        for (int i = 0; i < 16; ++i) tt += s.wsum[i];
        bsum[blk] = tt;
    }
}

// Local exclusive scan of bsum[0..nsc) -> s.gbl (chunk offsets).
__device__ void local_bscan(SM& s, int t, const int* __restrict__ bsum, int nsc) {
    int bd = 0;
    if (t < 256) { bd = (t < nsc) ? bsum[t] : 0; s.ps[t] = bd; }
    __syncthreads();
    for (int off = 1; off < 256; off <<= 1) {
        int v = (t < 256 && t >= off) ? s.ps[t - off] : 0;
        __syncthreads();
        if (t < 256) s.ps[t] += v;
        __syncthreads();
    }
    if (t < 256) s.gbl[t] = s.ps[t] - bd;
    __syncthreads();
}

// ---- Phase 3: LDS-binned scatter to key-sorted tbuf (coalesced writes).
__device__ void phase_scatter(SM& s, int blk, int t,
                              const int* __restrict__ src,
                              const int* __restrict__ dst,
                              const int* __restrict__ gh,
                              const int* __restrict__ bsum,
                              unsigned* __restrict__ tbuf,
                              int ne, int neb, int M, int nt, int nsc) {
    local_bscan(s, t, bsum, nsc);
    int p0 = 0, c = 0;
    if (t < 512) {
        if (t < nt) {
            int idx = t * neb + blk;
            p0 = gh[idx] + s.gbl[idx >> 11];
            int p1 = (idx + 1 < M) ? (gh[idx + 1] + s.gbl[(idx + 1) >> 11]) : ne;
            c = p1 - p0;
        }
        s.u.p3.hD[t] = c;
    }
    __syncthreads();
    // exclusive scan over 512 keys: pair-sum + masked 256-wide Hillis-Steele
    int h0 = 0, h1 = 0;
    if (t < 256) { h0 = s.u.p3.hD[2 * t]; h1 = s.u.p3.hD[2 * t + 1]; s.ps[t] = h0 + h1; }
    __syncthreads();
    for (int off = 1; off < 256; off <<= 1) {
        int v = (t < 256 && t >= off) ? s.ps[t - off] : 0;
        __syncthreads();
        if (t < 256) s.ps[t] += v;
        __syncthreads();
    }
    if (t < 256) {
        int ex0 = s.ps[t] - h0 - h1;
        s.u.p3.cur[2 * t] = ex0;
        s.u.p3.cur[2 * t + 1] = ex0 + h0;
    }
    __syncthreads();
    if (t < 512) s.u.p3.hD[t] = p0 - s.u.p3.cur[t];  // lds-pos p -> global D[k]+p
    __syncthreads();

    int e0 = blk * EBLK;
    int e1 = e0 + EBLK; if (e1 > ne) e1 = ne;
    for (int i = e0 + t; i < e1; i += 1024) {
        int d = dst[i];
        int key = d >> TSH;
        int r = atomicAdd(&s.u.p3.cur[key], 1);
        s.u.p3.sval[r] = ((unsigned)src[i] << TSH) | (unsigned)(d & (TSZ - 1));
        s.u.p3.skey[r] = (unsigned short)key;
    }
    __syncthreads();
    int cnt = e1 - e0;
    for (int p = t; p < cnt; p += 1024)
        tbuf[s.u.p3.hD[s.u.p3.skey[p]] + p] = s.u.p3.sval[p];
}

// ---- Phase 4: per-tile exact-dst sort -> row_start + dst-sorted ebuf.
__device__ void phase_tsort(SM& s, int blk, int t,
                            const unsigned* __restrict__ tbuf,
                            const int* __restrict__ gh,
                            const int* __restrict__ bsum,
                            int* __restrict__ ebuf, int* __restrict__ rs,
                            int n, int ne, int neb, int nt, int nsc) {
    local_bscan(s, t, bsum, nsc);
    int tile = blk;
    int i0 = tile * neb;
    int ts = gh[i0] + s.gbl[i0 >> 11];
    int i1 = (tile + 1) * neb;
    int te = (tile + 1 < nt) ? gh[i1] + s.gbl[i1 >> 11] : ne;
    if (t < 256) s.u.p4.hist[t] = 0;
    __syncthreads();
    for (int i = ts + t; i < te; i += 1024)
        atomicAdd(&s.u.p4.hist[tbuf[i] & (TSZ - 1)], 1);
    __syncthreads();
    int d = 0;
    if (t < 256) { d = s.u.p4.hist[t]; s.ps[t] = d; }
    __syncthreads();
    for (int off = 1; off < 256; off <<= 1) {
        int v = (t < 256 && t >= off) ? s.ps[t - off] : 0;
        __syncthreads();
        if (t < 256) s.ps[t] += v;
        __syncthreads();
    }
    if (t < 256) {
        int ex = s.ps[t] - d;
        s.u.p4.cur[t] = ex;
        int node = tile * TSZ + t;
        if (node <= n) rs[node] = ts + ex;
    }
    __syncthreads();
    for (int i = ts + t; i < te; i += 1024) {
        unsigned p = tbuf[i];
        int dl = (int)(p & (TSZ - 1));
        int r = atomicAdd(&s.u.p4.cur[dl], 1);
        ebuf[ts + r] = (int)(p >> TSH);
    }
}

// ---- Phase 5: hn pack (all NB blocks, contiguous chunks, deg from rs diff).
__device__ void phase_hn(int blk, int t,
                         const float* __restrict__ hsrc,
                         const int* __restrict__ rs,
                         float2* __restrict__ hn, int n32) {
    int chunk = (n32 + NB - 1) / NB;
    int q0 = blk * chunk;
    int q1 = q0 + chunk; if (q1 > n32) q1 = n32;
    for (int q = q0 + t; q < q1; q += 1024) {
        int node = q >> 5;
        int dg = rs[node + 1] - rs[node];
        float sc = rsqrtf((float)(dg > 1 ? dg : 1));
        f32x4v v = __builtin_nontemporal_load((const f32x4v*)hsrc + q);
        union { __half2 h2[2]; float2 f2; } u2;
        u2.h2[0] = __floats2half2_rn(v.x * sc, v.y * sc);
        u2.h2[1] = __floats2half2_rn(v.z * sc, v.w * sc);
        hn[q] = u2.f2;
    }
}

// ---- Cooperative mega-kernel: all preprocessing, one dispatch.
__global__ __launch_bounds__(1024, 8) void preproc_all(
    const int* __restrict__ src, const int* __restrict__ dst,
    const float* __restrict__ hsrc, const float* __restrict__ W,
    _Float16* __restrict__ Wf, int* __restrict__ gh, int* __restrict__ bsum,
    unsigned* __restrict__ tbuf, int* __restrict__ ebuf, int* __restrict__ rs,
    float2* __restrict__ hn,
    int n, int ne, int nt, int neb, int M, int nsc, int n32) {
    __shared__ SM s;
    cg::grid_group grid = cg::this_grid();
    int blk = blockIdx.x, t = threadIdx.x;

    phase_hist(s, blk, t, dst, gh, ne, neb, nt, W, Wf);
    __threadfence(); grid.sync();
    if (blk < nsc) phase_scan(s, blk, t, gh, bsum, M);
    __threadfence(); grid.sync();
    if (blk < neb) phase_scatter(s, blk, t, src, dst, gh, bsum, tbuf, ne, neb, M, nt, nsc);
    __threadfence(); grid.sync();
    if (blk < nt) phase_tsort(s, blk, t, tbuf, gh, bsum, ebuf, rs, n, ne, neb, nt, nsc);
    __threadfence(); grid.sync();
    phase_hn(blk, t, hsrc, rs, hn, n32);
}

// ---- Fallback thin kernels (used only if cooperative launch fails).
__global__ __launch_bounds__(1024) void k_hist(const int* dst, int* gh, int ne,
                                               int neb, int nt, const float* W,
                                               _Float16* Wf) {
    __shared__ SM s;
    phase_hist(s, blockIdx.x, threadIdx.x, dst, gh, ne, neb, nt, W, Wf);
}
__global__ __launch_bounds__(1024) void k_scan(int* g, int* bsum, int M) {
    __shared__ SM s;
    phase_scan(s, blockIdx.x, threadIdx.x, g, bsum, M);
}
__global__ __launch_bounds__(1024) void k_scat(const int* src, const int* dst,
                                               const int* gh, const int* bsum,
                                               unsigned* tbuf, int ne, int neb,
                                               int M, int nt, int nsc) {
    __shared__ SM s;
    phase_scatter(s, blockIdx.x, threadIdx.x, src, dst, gh, bsum, tbuf, ne, neb, M, nt, nsc);
}
__global__ __launch_bounds__(1024) void k_tsort(const unsigned* tbuf, const int* gh,
                                                const int* bsum, int* ebuf, int* rs,
                                                int n, int ne, int neb, int nt, int nsc) {
    __shared__ SM s;
    phase_tsort(s, blockIdx.x, threadIdx.x, tbuf, gh, bsum, ebuf, rs, n, ne, neb, nt, nsc);
}
__global__ __launch_bounds__(1024) void k_hn(const float* hsrc, const int* rs,
                                             float2* hn, int n32) {
    phase_hn(blockIdx.x, threadIdx.x, hsrc, rs, hn, n32);
}

// Phase 1: 16 groups x 32 lanes; group g aggregates 4 nodes {blk*64+it*16+g}
// (degree averaging over 4 draws -> balanced barrier), x8-unrolled loads.
// Fabric-bound at ~3.2TB/s random lines (round-1 A/B) -> proven structure kept.
// Phase 2: 8 waves; wave w = col-tile; 4 row-tiles x 4 chained
// mfma_f32_16x16x32_f16 (K=128), bf reused across row-tiles. NT out stores.
__global__ __launch_bounds__(512) void gather_gemm(const float2* __restrict__ hn,
                                                   const int* __restrict__ ebuf,
                                                   const int* __restrict__ rs,
                                                   const _Float16* __restrict__ Wf,
                                                   const float* __restrict__ b,
                                                   float* __restrict__ out, int n) {
    __shared__ _Float16 xs[64 * 136];
    int tid = threadIdx.x;
    int g = tid >> 5, lane = tid & 31;

#pragma unroll
    for (int it = 0; it < 4; ++it) {
        int row = it * 16 + g;
        int node = blockIdx.x * 64 + row;
        union { __half2 h2[2]; float2 f2; } u;
        if (node < n) {
            int s0 = rs[node];
            int s1 = rs[node + 1];
            __half2 a0 = __floats2half2_rn(0.f, 0.f), a1 = a0;
            int i = s0;
            for (; i + 7 < s1; i += 8) {
                int e0 = ebuf[i], e1 = ebuf[i + 1], e2 = ebuf[i + 2], e3 = ebuf[i + 3];
                int e4 = ebuf[i + 4], e5 = ebuf[i + 5], e6 = ebuf[i + 6], e7 = ebuf[i + 7];
                float2 r0 = hn[(size_t)e0 * 32 + lane];
                float2 r1 = hn[(size_t)e1 * 32 + lane];
                float2 r2 = hn[(size_t)e2 * 32 + lane];
                float2 r3 = hn[(size_t)e3 * 32 + lane];
                float2 r4 = hn[(size_t)e4 * 32 + lane];
                float2 r5 = hn[(size_t)e5 * 32 + lane];
                float2 r6 = hn[(size_t)e6 * 32 + lane];
                float2 r7 = hn[(size_t)e7 * 32 + lane];
                const __half2* q0 = (const __half2*)&r0;
                const __half2* q1 = (const __half2*)&r1;
                const __half2* q2 = (const __half2*)&r2;
                const __half2* q3 = (const __half2*)&r3;
                const __half2* q4 = (const __half2*)&r4;
                const __half2* q5 = (const __half2*)&r5;
                const __half2* q6 = (const __half2*)&r6;
                const __half2* q7 = (const __half2*)&r7;
                a0 = __hadd2(a0, q0[0]); a1 = __hadd2(a1, q0[1]);
                a0 = __hadd2(a0, q1[0]); a1 = __hadd2(a1, q1[1]);
                a0 = __hadd2(a0, q2[0]); a1 = __hadd2(a1, q2[1]);
                a0 = __hadd2(a0, q3[0]); a1 = __hadd2(a1, q3[1]);
                a0 = __hadd2(a0, q4[0]); a1 = __hadd2(a1, q4[1]);
                a0 = __hadd2(a0, q5[0]); a1 = __hadd2(a1, q5[1]);
                a0 = __hadd2(a0, q6[0]); a1 = __hadd2(a1, q6[1]);
                a0 = __hadd2(a0, q7[0]); a1 = __hadd2(a1, q7[1]);
            }
            for (; i + 3 < s1; i += 4) {
                int e0 = ebuf[i], e1 = ebuf[i + 1], e2 = ebuf[i + 2], e3 = ebuf[i + 3];
                float2 r0 = hn[(size_t)e0 * 32 + lane];
                float2 r1 = hn[(size_t)e1 * 32 + lane];
                float2 r2 = hn[(size_t)e2 * 32 + lane];
                float2 r3 = hn[(size_t)e3 * 32 + lane];
                const __half2* q0 = (const __half2*)&r0;
                const __half2* q1 = (const __half2*)&r1;
                const __half2* q2 = (const __half2*)&r2;
                const __half2* q3 = (const __half2*)&r3;
                a0 = __hadd2(a0, q0[0]); a1 = __hadd2(a1, q0[1]);
                a0 = __hadd2(a0, q1[0]); a1 = __hadd2(a1, q1[1]);
                a0 = __hadd2(a0, q2[0]); a1 = __hadd2(a1, q2[1]);
                a0 = __hadd2(a0, q3[0]); a1 = __hadd2(a1, q3[1]);
            }
            for (; i < s1; ++i) {
                int e0 = ebuf[i];
                float2 r0 = hn[(size_t)e0 * 32 + lane];
                const __half2* q0 = (const __half2*)&r0;
                a0 = __hadd2(a0, q0[0]); a1 = __hadd2(a1, q0[1]);
            }
            int dn = s1 - s0;
            float nd = rsqrtf((float)(dn > 1 ? dn : 1));
            float2 f0 = __half22float2(a0), f1 = __half22float2(a1);
            u.h2[0] = __floats2half2_rn(f0.x * nd, f0.y * nd);
            u.h2[1] = __floats2half2_rn(f1.x * nd, f1.y * nd);
        } else {
            u.h2[0] = __floats2half2_rn(0.f, 0.f);
            u.h2[1] = u.h2[0];
        }
        *(float2*)(xs + row * 136 + lane * 4) = u.f2;
    }
    __syncthreads();

    int w = tid >> 6;     // wave = col-tile
    int wl = tid & 63;
    int cn = wl & 15;
    int quad = wl >> 4;

    f32x4 acc[4] = {{0.f, 0.f, 0.f, 0.f}, {0.f, 0.f, 0.f, 0.f},
                    {0.f, 0.f, 0.f, 0.f}, {0.f, 0.f, 0.f, 0.f}};
#pragma unroll
    for (int kk = 0; kk < 4; ++kk) {
        half8_t bf = ((const half8_t*)Wf)[(w * 4 + kk) * 64 + wl];
#pragma unroll
        for (int rt = 0; rt < 4; ++rt) {
            half8_t af = *(const half8_t*)(xs + (rt * 16 + cn) * 136 + kk * 32 + quad * 8);
            acc[rt] = __builtin_amdgcn_mfma_f32_16x16x32_f16(af, bf, acc[rt], 0, 0, 0);
        }
    }
    float bj = b[w * 16 + cn];
    int node0 = blockIdx.x * 64;
#pragma unroll
    for (int rt = 0; rt < 4; ++rt) {
#pragma unroll
        for (int r = 0; r < 4; ++r) {
            int node = node0 + rt * 16 + quad * 4 + r;
            if (node < n)
                __builtin_nontemporal_store(acc[rt][r] + bj,
                                            &out[(size_t)node * DIM + w * 16 + cn]);
        }
    }
}

extern "C" void kernel_launch(void* const* d_in, const int* in_sizes, int n_in,
                              void* d_out, int out_size, void* d_ws, size_t ws_size,
                              hipStream_t stream) {
    const float* h = (const float*)d_in[0];
    const float* W = (const float*)d_in[1];
    const float* b = (const float*)d_in[2];
    const int* esrc = (const int*)d_in[3];
    const int* edst = (const int*)d_in[4];
    float* out = (float*)d_out;

    int n = in_sizes[0] / DIM;   // 100000
    int ne = in_sizes[3];        // 1600000
    int n32 = n * 32;

    int neb = (ne + EBLK - 1) / EBLK;     // 500
    int nt = (n + TSZ - 1) >> TSH;        // 391
    int M = nt * neb;                     // 195500
    int nsc = (M + SCH - 1) / SCH;        // 96

    float2* hn = (float2*)d_ws;                       // n*32 float2 (25.6MB)
    _Float16* Wf = (_Float16*)(hn + (size_t)n * 32);  // 16384 halfs
    int* rs = (int*)(Wf + 16384);                     // n+1 (padded)
    int* gh = rs + ((n + 4) & ~3);                    // M
    int* bsum = gh + ((M + 3) & ~3);                  // 256
    unsigned* tbuf = (unsigned*)(bsum + 256);         // ne
    int* ebuf = (int*)(tbuf + ne);                    // ne

    void* kargs[] = {
        (void*)&esrc, (void*)&edst, (void*)&h, (void*)&W,
        (void*)&Wf, (void*)&gh, (void*)&bsum, (void*)&tbuf, (void*)&ebuf,
        (void*)&rs, (void*)&hn,
        (void*)&n, (void*)&ne, (void*)&nt, (void*)&neb, (void*)&M,
        (void*)&nsc, (void*)&n32
    };
    hipError_t err = hipLaunchCooperativeKernel((const void*)preproc_all,
                                                dim3(NB), dim3(1024),
                                                kargs, 0, stream);
    if (err != hipSuccess) {
        (void)hipGetLastError();  // clear; fall back to split pipeline
        k_hist<<<neb + 2, 1024, 0, stream>>>(edst, gh, ne, neb, nt, W, Wf);
        k_scan<<<nsc, 1024, 0, stream>>>(gh, bsum, M);
        k_scat<<<neb, 1024, 0, stream>>>(esrc, edst, gh, bsum, tbuf, ne, neb, M, nt, nsc);
        k_tsort<<<nt, 1024, 0, stream>>>(tbuf, gh, bsum, ebuf, rs, n, ne, neb, nt, nsc);
        k_hn<<<NB, 1024, 0, stream>>>(h, rs, hn, n32);
    }
    gather_gemm<<<(n + 63) / 64, 512, 0, stream>>>(hn, ebuf, rs, Wf, b, out, n);
}

// Round 7
// 272.210 us; speedup vs baseline: 4.4129x; 4.4129x over previous
//
#include <hip/hip_runtime.h>
#include <hip/hip_fp16.h>

#define DIM 128
#define TSH 8
#define TSZ 256    // dst-tile size (nodes per tile)
#define EBLK 4096  // edges per hist/scatter block
#define CAP 4608   // LDS edge-list capacity per tile (mean 4092, +8 sigma)

typedef _Float16 half8_t __attribute__((ext_vector_type(8)));
typedef float f32x4 __attribute__((ext_vector_type(4)));
typedef float f32x4v __attribute__((ext_vector_type(4)));

// ws: hn f16[n*128] (25.6MB) | Wf f16[16384] | deg i32[n] | gh i32[nt*neb] |
//     bsum i32[256] | tbuf u32[ne]
// Assumptions (n=100000, ne=1.6M): nt=391<=512, nsc=150<=256.
// NOTE (round 6): cooperative grid.sync costs ~260us/sync on 8-XCD MI355X
// (cross-L2 coherence) -> phase fusion via kernel boundaries only.

// Blocks [0,neb): LDS histogram of dst-tile key -> gh[key*neb+blk], plus
// exact per-node degree via fire-and-forget global atomics (deg pre-zeroed).
// Blocks [neb,neb+2): Wf table:
// Wf[((ct*4+kk)*64+lane)*8+j] = W[ct*16+(lane&15)][kk*32+(lane>>4)*8+j]
__global__ __launch_bounds__(1024) void k1_hist(const int* __restrict__ dst,
                                                int* __restrict__ gh,
                                                int* __restrict__ deg,
                                                int ne, int neb, int nt,
                                                const float* __restrict__ W,
                                                _Float16* __restrict__ Wf) {
    __shared__ int h[512];
    int t = threadIdx.x, blk = blockIdx.x;
    if (blk >= neb) {
        int idx = (blk - neb) * 1024 + t;  // 0..2047
        int ct = idx >> 8, kk = (idx >> 6) & 3, lane = idx & 63;
        int nn = lane & 15, quad = lane >> 4;
        const float* wr = W + (ct * 16 + nn) * DIM + kk * 32 + quad * 8;
        _Float16* o = Wf + (size_t)idx * 8;
#pragma unroll
        for (int j = 0; j < 8; ++j) o[j] = (_Float16)wr[j];
        return;
    }
    if (t < 512) h[t] = 0;
    __syncthreads();
    int e0 = blk * EBLK;
    int e1 = e0 + EBLK; if (e1 > ne) e1 = ne;
    for (int i = e0 + t; i < e1; i += 1024) {
        int d = dst[i];
        atomicAdd(&h[d >> TSH], 1);
        atomicAdd(&deg[d], 1);
    }
    __syncthreads();
    for (int k = t; k < nt; k += 1024) gh[k * neb + blk] = h[k];
}

// Blocks [0,nsc): exclusive scan of gh in 1024-chunks; bsum[chunk] = raw total.
// Blocks [nsc,..): hn pack: hn[i] = f16(h[i] * rsqrt(max(deg,1))).
__global__ __launch_bounds__(1024) void k2_scan_hn(int* __restrict__ g,
                                                   int* __restrict__ bsum,
                                                   int M, int nsc,
                                                   const int* __restrict__ deg,
                                                   const float* __restrict__ hsrc,
                                                   float2* __restrict__ hn,
                                                   int n32) {
    int t = threadIdx.x, blk = blockIdx.x;
    if (blk < nsc) {
        __shared__ int wsum[16];
        int base = blk * 1024 + t;
        int v = (base < M) ? g[base] : 0;
        int lane = t & 63, wv = t >> 6;
        int x = v;
#pragma unroll
        for (int off = 1; off < 64; off <<= 1) {
            int y = __shfl_up(x, off, 64);
            if (lane >= off) x += y;
        }
        if (lane == 63) wsum[wv] = x;
        __syncthreads();
        int woff = 0;
        for (int i = 0; i < wv; ++i) woff += wsum[i];
        if (base < M) g[base] = woff + x - v;
        if (t == 0) {
            int s = 0;
#pragma unroll
            for (int i = 0; i < 16; ++i) s += wsum[i];
            bsum[blk] = s;
        }
        return;
    }
    int q = (blk - nsc) * 1024 + t;
    if (q < n32) {
        int node = q >> 5;
        int dg = deg[node];
        float sc = rsqrtf((float)(dg > 1 ? dg : 1));
        f32x4v v = __builtin_nontemporal_load((const f32x4v*)hsrc + q);
        union { __half2 h2[2]; float2 f2; } u;
        u.h2[0] = __floats2half2_rn(v.x * sc, v.y * sc);
        u.h2[1] = __floats2half2_rn(v.z * sc, v.w * sc);
        hn[q] = u.f2;
    }
}

// LDS-binned scatter to key-sorted tbuf (coalesced writes). Round-4 proven.
__global__ __launch_bounds__(1024) void k3_scatter(const int* __restrict__ src,
                                                   const int* __restrict__ dst,
                                                   const int* __restrict__ gh,
                                                   const int* __restrict__ bsum,
                                                   unsigned* __restrict__ tbuf,
                                                   int ne, int neb, int M, int nt,
                                                   int nsc) {
    __shared__ int hD[512];
    __shared__ int ps[256];
    __shared__ int cur[512];
    __shared__ int gbl[256];
    __shared__ unsigned sval[EBLK];        // 16KB
    __shared__ unsigned short skey[EBLK];  // 8KB
    int t = threadIdx.x, blk = blockIdx.x;

    int bd = 0;
    if (t < 256) { bd = (t < nsc) ? bsum[t] : 0; ps[t] = bd; }
    __syncthreads();
    for (int off = 1; off < 256; off <<= 1) {
        int v = (t < 256 && t >= off) ? ps[t - off] : 0;
        __syncthreads();
        if (t < 256) ps[t] += v;
        __syncthreads();
    }
    if (t < 256) gbl[t] = ps[t] - bd;
    __syncthreads();

    int p0 = 0, c = 0;
    if (t < 512) {
        if (t < nt) {
            int idx = t * neb + blk;
            p0 = gh[idx] + gbl[idx >> 10];
            int p1 = (idx + 1 < M) ? (gh[idx + 1] + gbl[(idx + 1) >> 10]) : ne;
            c = p1 - p0;
        }
        hD[t] = c;
    }
    __syncthreads();
    int h0 = 0, h1 = 0;
    if (t < 256) { h0 = hD[2 * t]; h1 = hD[2 * t + 1]; ps[t] = h0 + h1; }
    __syncthreads();
    for (int off = 1; off < 256; off <<= 1) {
        int v = (t < 256 && t >= off) ? ps[t - off] : 0;
        __syncthreads();
        if (t < 256) ps[t] += v;
        __syncthreads();
    }
    if (t < 256) {
        int ex0 = ps[t] - h0 - h1;
        cur[2 * t] = ex0;
        cur[2 * t + 1] = ex0 + h0;
    }
    __syncthreads();
    if (t < 512) hD[t] = p0 - cur[t];  // lds-pos p -> global pos hD[k]+p
    __syncthreads();

    int e0 = blk * EBLK;
    int e1 = e0 + EBLK; if (e1 > ne) e1 = ne;
    for (int i = e0 + t; i < e1; i += 1024) {
        int d = dst[i];
        int key = d >> TSH;
        int r = atomicAdd(&cur[key], 1);
        sval[r] = ((unsigned)src[i] << TSH) | (unsigned)(d & (TSZ - 1));
        skey[r] = (unsigned short)key;
    }
    __syncthreads();
    int cnt = e1 - e0;
    for (int p = t; p < cnt; p += 1024)
        tbuf[hD[skey[p]] + p] = sval[p];
}

// Fused per-tile kernel: exact-dst LDS sort -> register aggregation of hn rows
// (fabric-bound gather) -> MFMA epilogue, in two 128-row halves.
// LDS ~58KB -> 2 blocks/CU, 391 blocks = single occupancy round.
__global__ __launch_bounds__(1024) void k4_tile_gemm(
        const unsigned* __restrict__ tbuf,
        const int* __restrict__ gh, const int* __restrict__ bsum,
        const float2* __restrict__ hn, const _Float16* __restrict__ Wf,
        const float* __restrict__ b, float* __restrict__ out,
        int n, int ne, int neb, int nt, int nsc, int M) {
    __shared__ int gbl[256];
    __shared__ int ps[256];
    __shared__ int hist[TSZ];
    __shared__ int sst[TSZ];
    __shared__ int cur[TSZ];
    __shared__ float scl[TSZ];
    __shared__ unsigned elB[CAP];          // 18KB
    __shared__ _Float16 xs[128 * 136];     // 34.8KB (one half)
    int t = threadIdx.x, tile = blockIdx.x;

    int bd = 0;
    if (t < 256) { bd = (t < nsc) ? bsum[t] : 0; ps[t] = bd; hist[t] = 0; }
    __syncthreads();
    for (int off = 1; off < 256; off <<= 1) {
        int v = (t < 256 && t >= off) ? ps[t - off] : 0;
        __syncthreads();
        if (t < 256) ps[t] += v;
        __syncthreads();
    }
    if (t < 256) gbl[t] = ps[t] - bd;
    __syncthreads();

    int i0 = tile * neb;
    int ts = gh[i0] + gbl[i0 >> 10];
    int i1 = (tile + 1) * neb;
    int te = (tile + 1 < nt) ? gh[i1] + gbl[i1 >> 10] : ne;
    int cnt = te - ts;

    // exact-dst histogram (tbuf pass 1); hist[dl] == in-degree of the node
    for (int i = ts + t; i < te; i += 1024)
        atomicAdd(&hist[tbuf[i] & (TSZ - 1)], 1);
    __syncthreads();
    int d = 0;
    if (t < 256) { d = hist[t]; ps[t] = d; }
    __syncthreads();
    for (int off = 1; off < 256; off <<= 1) {
        int v = (t < 256 && t >= off) ? ps[t - off] : 0;
        __syncthreads();
        if (t < 256) ps[t] += v;
        __syncthreads();
    }
    if (t < 256) {
        int ex = ps[t] - d;
        sst[t] = ex;
        cur[t] = ex;
        scl[t] = rsqrtf((float)(d > 1 ? d : 1));
    }
    __syncthreads();

    const _Float16* hp = (const _Float16*)hn;
    int g = t >> 4, lane = t & 15;
    int w = t >> 6, wl = t & 63, cn = wl & 15, quad = wl >> 4;
    int ct = w & 7, rhg = w >> 3;

    bool fast = (cnt <= CAP);
    if (fast) {
        // rank-scatter into dst-sorted LDS list (tbuf pass 2)
        for (int i = ts + t; i < te; i += 1024) {
            unsigned p = tbuf[i];
            int dl = (int)(p & (TSZ - 1));
            int r = atomicAdd(&cur[dl], 1);
            elB[r] = p >> TSH;  // src node
        }
        __syncthreads();
    }

    for (int hh = 0; hh < 2; ++hh) {
        // aggregate 128 nodes of this half into xs
#pragma unroll
        for (int it = 0; it < 2; ++it) {
            int dl = hh * 128 + it * 64 + g;
            half8_t acc = {(_Float16)0, (_Float16)0, (_Float16)0, (_Float16)0,
                           (_Float16)0, (_Float16)0, (_Float16)0, (_Float16)0};
            if (fast) {
                int s0 = sst[dl], c = hist[dl];
                int j = s0, jend = s0 + c;
                for (; j + 7 < jend; j += 8) {
                    int e0 = elB[j], e1 = elB[j + 1], e2 = elB[j + 2], e3 = elB[j + 3];
                    int e4 = elB[j + 4], e5 = elB[j + 5], e6 = elB[j + 6], e7 = elB[j + 7];
                    half8_t r0 = *(const half8_t*)(hp + (size_t)e0 * 128 + lane * 8);
                    half8_t r1 = *(const half8_t*)(hp + (size_t)e1 * 128 + lane * 8);
                    half8_t r2 = *(const half8_t*)(hp + (size_t)e2 * 128 + lane * 8);
                    half8_t r3 = *(const half8_t*)(hp + (size_t)e3 * 128 + lane * 8);
                    half8_t r4 = *(const half8_t*)(hp + (size_t)e4 * 128 + lane * 8);
                    half8_t r5 = *(const half8_t*)(hp + (size_t)e5 * 128 + lane * 8);
                    half8_t r6 = *(const half8_t*)(hp + (size_t)e6 * 128 + lane * 8);
                    half8_t r7 = *(const half8_t*)(hp + (size_t)e7 * 128 + lane * 8);
                    acc += r0; acc += r1; acc += r2; acc += r3;
                    acc += r4; acc += r5; acc += r6; acc += r7;
                }
                for (; j < jend; ++j) {
                    int e0 = elB[j];
                    acc += *(const half8_t*)(hp + (size_t)e0 * 128 + lane * 8);
                }
            } else {
                // overflow fallback (statistically never): filter-scan from global
                for (int j = ts; j < te; ++j) {
                    unsigned p = tbuf[j];
                    if ((int)(p & (TSZ - 1)) == dl) {
                        int e0 = (int)(p >> TSH);
                        acc += *(const half8_t*)(hp + (size_t)e0 * 128 + lane * 8);
                    }
                }
            }
            float nd = scl[dl];
            half8_t o;
#pragma unroll
            for (int k2 = 0; k2 < 8; ++k2) o[k2] = (_Float16)((float)acc[k2] * nd);
            *(half8_t*)(xs + (it * 64 + g) * 136 + lane * 8) = o;
        }
        __syncthreads();

        // GEMM this 128-row half: wave = (row-half-group, col-tile)
        f32x4 acc4[4] = {{0.f, 0.f, 0.f, 0.f}, {0.f, 0.f, 0.f, 0.f},
                         {0.f, 0.f, 0.f, 0.f}, {0.f, 0.f, 0.f, 0.f}};
#pragma unroll
        for (int kk = 0; kk < 4; ++kk) {
            half8_t bf = ((const half8_t*)Wf)[(ct * 4 + kk) * 64 + wl];
#pragma unroll
            for (int rt = 0; rt < 4; ++rt) {
                half8_t af = *(const half8_t*)(xs + (rhg * 64 + rt * 16 + cn) * 136 +
                                               kk * 32 + quad * 8);
                acc4[rt] = __builtin_amdgcn_mfma_f32_16x16x32_f16(af, bf, acc4[rt], 0, 0, 0);
            }
        }
        float bj = b[ct * 16 + cn];
        int node0 = tile * TSZ + hh * 128 + rhg * 64;
#pragma unroll
        for (int rt = 0; rt < 4; ++rt) {
#pragma unroll
            for (int r = 0; r < 4; ++r) {
                int node = node0 + rt * 16 + quad * 4 + r;
                if (node < n)
                    __builtin_nontemporal_store(acc4[rt][r] + bj,
                                                &out[(size_t)node * DIM + ct * 16 + cn]);
            }
        }
        __syncthreads();  // xs reused by next half
    }
}

extern "C" void kernel_launch(void* const* d_in, const int* in_sizes, int n_in,
                              void* d_out, int out_size, void* d_ws, size_t ws_size,
                              hipStream_t stream) {
    const float* h = (const float*)d_in[0];
    const float* W = (const float*)d_in[1];
    const float* b = (const float*)d_in[2];
    const int* esrc = (const int*)d_in[3];
    const int* edst = (const int*)d_in[4];
    float* out = (float*)d_out;

    int n = in_sizes[0] / DIM;   // 100000
    int ne = in_sizes[3];        // 1600000
    int n32 = n * 32;

    int neb = (ne + EBLK - 1) / EBLK;     // 391
    int nt = (n + TSZ - 1) >> TSH;        // 391
    int M = nt * neb;                     // 152881
    int nsc = (M + 1023) / 1024;          // 150

    float2* hn = (float2*)d_ws;                       // n*32 float2 (25.6MB)
    _Float16* Wf = (_Float16*)(hn + (size_t)n * 32);  // 16384 halfs
    int* deg = (int*)(Wf + 16384);                    // n
    int* gh = deg + ((n + 3) & ~3);                   // M
    int* bsum = gh + ((M + 3) & ~3);                  // 256
    unsigned* tbuf = (unsigned*)(bsum + 256);         // ne

    hipMemsetAsync(deg, 0, (size_t)n * sizeof(int), stream);
    k1_hist<<<neb + 2, 1024, 0, stream>>>(edst, gh, deg, ne, neb, nt, W, Wf);
    k2_scan_hn<<<nsc + (n32 + 1023) / 1024, 1024, 0, stream>>>(gh, bsum, M, nsc,
                                                               deg, h, hn, n32);
    k3_scatter<<<neb, 1024, 0, stream>>>(esrc, edst, gh, bsum, tbuf, ne, neb, M, nt, nsc);
    k4_tile_gemm<<<nt, 1024, 0, stream>>>(tbuf, gh, bsum, hn, Wf, b, out,
                                          n, ne, neb, nt, nsc, M);
}

// Round 8
// 215.312 us; speedup vs baseline: 5.5791x; 1.2643x over previous
//
#include <hip/hip_runtime.h>
#include <hip/hip_fp16.h>

#define DIM 128
#define TSH 8
#define TSZ 256    // dst-tile size (nodes per tile)
#define EBLK 4096  // edges per hist/scatter block
#define CAP 4608   // LDS edge-list capacity per tile (mean 4092, +8 sigma)

typedef _Float16 half8_t __attribute__((ext_vector_type(8)));
typedef float f32x4 __attribute__((ext_vector_type(4)));
typedef float f32x4v __attribute__((ext_vector_type(4)));

// ws: hn f16[n*128] (25.6MB) | Wf f16[16384] | gh i32[nt*neb] | bsum i32[256] |
//     tbuf u32[ne]
// Assumptions (n=100000, ne=1.6M): nt=391<=512, nsc=150<=256.
// Poisons (measured): per-edge global atomics (r5/r7: ~150us); grid.sync (r6:
// ~260us/sync). Neither appears below.

// Blocks [0,neb): LDS histogram of dst-tile key -> gh[key*neb+blk].
// Blocks [neb,neb+2): Wf table:
// Wf[((ct*4+kk)*64+lane)*8+j] = W[ct*16+(lane&15)][kk*32+(lane>>4)*8+j]
__global__ __launch_bounds__(1024) void k1_hist(const int* __restrict__ dst,
                                                int* __restrict__ gh,
                                                int ne, int neb, int nt,
                                                const float* __restrict__ W,
                                                _Float16* __restrict__ Wf) {
    __shared__ int h[512];
    int t = threadIdx.x, blk = blockIdx.x;
    if (blk >= neb) {
        int idx = (blk - neb) * 1024 + t;  // 0..2047
        int ct = idx >> 8, kk = (idx >> 6) & 3, lane = idx & 63;
        int nn = lane & 15, quad = lane >> 4;
        const float* wr = W + (ct * 16 + nn) * DIM + kk * 32 + quad * 8;
        _Float16* o = Wf + (size_t)idx * 8;
#pragma unroll
        for (int j = 0; j < 8; ++j) o[j] = (_Float16)wr[j];
        return;
    }
    if (t < 512) h[t] = 0;
    __syncthreads();
    int e0 = blk * EBLK;
    int e1 = e0 + EBLK; if (e1 > ne) e1 = ne;
    for (int i = e0 + t; i < e1; i += 1024)
        atomicAdd(&h[dst[i] >> TSH], 1);
    __syncthreads();
    for (int k = t; k < nt; k += 1024) gh[k * neb + blk] = h[k];
}

// Exclusive scan of gh in 1024-chunks; bsum[chunk] = raw chunk total.
__global__ __launch_bounds__(1024) void k2_scan(int* __restrict__ g,
                                                int* __restrict__ bsum, int M) {
    __shared__ int wsum[16];
    int t = threadIdx.x, blk = blockIdx.x;
    int base = blk * 1024 + t;
    int v = (base < M) ? g[base] : 0;
    int lane = t & 63, wv = t >> 6;
    int x = v;
#pragma unroll
    for (int off = 1; off < 64; off <<= 1) {
        int y = __shfl_up(x, off, 64);
        if (lane >= off) x += y;
    }
    if (lane == 63) wsum[wv] = x;
    __syncthreads();
    int woff = 0;
    for (int i = 0; i < wv; ++i) woff += wsum[i];
    if (base < M) g[base] = woff + x - v;
    if (t == 0) {
        int s = 0;
#pragma unroll
        for (int i = 0; i < 16; ++i) s += wsum[i];
        bsum[blk] = s;
    }
}

// LDS-binned scatter to key-sorted tbuf (coalesced writes). Round-4/7 proven.
__global__ __launch_bounds__(1024) void k3_scatter(const int* __restrict__ src,
                                                   const int* __restrict__ dst,
                                                   const int* __restrict__ gh,
                                                   const int* __restrict__ bsum,
                                                   unsigned* __restrict__ tbuf,
                                                   int ne, int neb, int M, int nt,
                                                   int nsc) {
    __shared__ int hD[512];
    __shared__ int ps[256];
    __shared__ int cur[512];
    __shared__ int gbl[256];
    __shared__ unsigned sval[EBLK];        // 16KB
    __shared__ unsigned short skey[EBLK];  // 8KB
    int t = threadIdx.x, blk = blockIdx.x;

    int bd = 0;
    if (t < 256) { bd = (t < nsc) ? bsum[t] : 0; ps[t] = bd; }
    __syncthreads();
    for (int off = 1; off < 256; off <<= 1) {
        int v = (t < 256 && t >= off) ? ps[t - off] : 0;
        __syncthreads();
        if (t < 256) ps[t] += v;
        __syncthreads();
    }
    if (t < 256) gbl[t] = ps[t] - bd;
    __syncthreads();

    int p0 = 0, c = 0;
    if (t < 512) {
        if (t < nt) {
            int idx = t * neb + blk;
            p0 = gh[idx] + gbl[idx >> 10];
            int p1 = (idx + 1 < M) ? (gh[idx + 1] + gbl[(idx + 1) >> 10]) : ne;
            c = p1 - p0;
        }
        hD[t] = c;
    }
    __syncthreads();
    int h0 = 0, h1 = 0;
    if (t < 256) { h0 = hD[2 * t]; h1 = hD[2 * t + 1]; ps[t] = h0 + h1; }
    __syncthreads();
    for (int off = 1; off < 256; off <<= 1) {
        int v = (t < 256 && t >= off) ? ps[t - off] : 0;
        __syncthreads();
        if (t < 256) ps[t] += v;
        __syncthreads();
    }
    if (t < 256) {
        int ex0 = ps[t] - h0 - h1;
        cur[2 * t] = ex0;
        cur[2 * t + 1] = ex0 + h0;
    }
    __syncthreads();
    if (t < 512) hD[t] = p0 - cur[t];  // lds-pos p -> global pos hD[k]+p
    __syncthreads();

    int e0 = blk * EBLK;
    int e1 = e0 + EBLK; if (e1 > ne) e1 = ne;
    for (int i = e0 + t; i < e1; i += 1024) {
        int d = dst[i];
        int key = d >> TSH;
        int r = atomicAdd(&cur[key], 1);
        sval[r] = ((unsigned)src[i] << TSH) | (unsigned)(d & (TSZ - 1));
        skey[r] = (unsigned short)key;
    }
    __syncthreads();
    int cnt = e1 - e0;
    for (int p = t; p < cnt; p += 1024)
        tbuf[hD[skey[p]] + p] = sval[p];
}

// One block per tile: exact-dst LDS histogram from own tbuf slice -> scl,
// then pack own 256 nodes' hn = f16(h * rsqrt(max(deg,1))). No atomics beyond
// LDS, no ebuf/rs. Contiguous h read (128KB/tile), coalesced hn write.
__global__ __launch_bounds__(1024) void k4_deg_hn(const unsigned* __restrict__ tbuf,
                                                  const int* __restrict__ gh,
                                                  const int* __restrict__ bsum,
                                                  const float* __restrict__ hsrc,
                                                  float2* __restrict__ hn,
                                                  int n, int ne, int neb, int nt,
                                                  int nsc) {
    __shared__ int ps[256];
    __shared__ int gbl[256];
    __shared__ int hist[TSZ];
    __shared__ float scl[TSZ];
    int t = threadIdx.x, tile = blockIdx.x;

    int bd = 0;
    if (t < 256) { bd = (t < nsc) ? bsum[t] : 0; ps[t] = bd; hist[t] = 0; }
    __syncthreads();
    for (int off = 1; off < 256; off <<= 1) {
        int v = (t < 256 && t >= off) ? ps[t - off] : 0;
        __syncthreads();
        if (t < 256) ps[t] += v;
        __syncthreads();
    }
    if (t < 256) gbl[t] = ps[t] - bd;
    __syncthreads();

    int i0 = tile * neb;
    int ts = gh[i0] + gbl[i0 >> 10];
    int i1 = (tile + 1) * neb;
    int te = (tile + 1 < nt) ? gh[i1] + gbl[i1 >> 10] : ne;

    for (int i = ts + t; i < te; i += 1024)
        atomicAdd(&hist[tbuf[i] & (TSZ - 1)], 1);
    __syncthreads();
    if (t < 256) {
        int d = hist[t];
        scl[t] = rsqrtf((float)(d > 1 ? d : 1));
    }
    __syncthreads();

    int qbase = tile * 8192;  // 256 nodes x 32 float4
    for (int q = t; q < 8192; q += 1024) {
        int node = tile * TSZ + (q >> 5);
        if (node < n) {
            f32x4v v = __builtin_nontemporal_load((const f32x4v*)hsrc + qbase + q);
            float sc = scl[q >> 5];
            union { __half2 h2[2]; float2 f2; } u;
            u.h2[0] = __floats2half2_rn(v.x * sc, v.y * sc);
            u.h2[1] = __floats2half2_rn(v.z * sc, v.w * sc);
            hn[qbase + q] = u.f2;
        }
    }
}

// Fused per-tile consumer: exact-dst LDS sort (tile-hist + rank-scatter into
// elB) -> fabric-bound gather of hn rows (32-lane x float2, round-0 proven
// structure) -> MFMA epilogue in two 128-row halves. LDS ~59KB -> 2 blocks/CU.
__global__ __launch_bounds__(1024) void k5_tile_gemm(
        const unsigned* __restrict__ tbuf,
        const int* __restrict__ gh, const int* __restrict__ bsum,
        const float2* __restrict__ hn, const _Float16* __restrict__ Wf,
        const float* __restrict__ b, float* __restrict__ out,
        int n, int ne, int neb, int nt, int nsc) {
    __shared__ int gbl[256];
    __shared__ int ps[256];
    __shared__ int hist[TSZ];
    __shared__ int sst[TSZ];
    __shared__ int cur[TSZ];
    __shared__ float scl[TSZ];
    __shared__ unsigned elB[CAP];          // 18KB
    __shared__ _Float16 xs[128 * 136];     // 34.8KB (one half)
    int t = threadIdx.x, tile = blockIdx.x;

    int bd = 0;
    if (t < 256) { bd = (t < nsc) ? bsum[t] : 0; ps[t] = bd; hist[t] = 0; }
    __syncthreads();
    for (int off = 1; off < 256; off <<= 1) {
        int v = (t < 256 && t >= off) ? ps[t - off] : 0;
        __syncthreads();
        if (t < 256) ps[t] += v;
        __syncthreads();
    }
    if (t < 256) gbl[t] = ps[t] - bd;
    __syncthreads();

    int i0 = tile * neb;
    int ts = gh[i0] + gbl[i0 >> 10];
    int i1 = (tile + 1) * neb;
    int te = (tile + 1 < nt) ? gh[i1] + gbl[i1 >> 10] : ne;
    int cnt = te - ts;

    // exact-dst histogram (tbuf pass 1); hist[dl] == in-degree
    for (int i = ts + t; i < te; i += 1024)
        atomicAdd(&hist[tbuf[i] & (TSZ - 1)], 1);
    __syncthreads();
    int d = 0;
    if (t < 256) { d = hist[t]; ps[t] = d; }
    __syncthreads();
    for (int off = 1; off < 256; off <<= 1) {
        int v = (t < 256 && t >= off) ? ps[t - off] : 0;
        __syncthreads();
        if (t < 256) ps[t] += v;
        __syncthreads();
    }
    if (t < 256) {
        int ex = ps[t] - d;
        sst[t] = ex;
        cur[t] = ex;
        scl[t] = rsqrtf((float)(d > 1 ? d : 1));
    }
    __syncthreads();

    bool fast = (cnt <= CAP);
    if (fast) {
        // rank-scatter into dst-sorted LDS list (tbuf pass 2)
        for (int i = ts + t; i < te; i += 1024) {
            unsigned p = tbuf[i];
            int dl = (int)(p & (TSZ - 1));
            int r = atomicAdd(&cur[dl], 1);
            elB[r] = p >> TSH;  // src node
        }
        __syncthreads();
    }

    int g2 = t >> 5, lane2 = t & 31;   // 32 groups x 32 lanes (gather)
    int w = t >> 6, wl = t & 63, cn = wl & 15, quad = wl >> 4;
    int ct = w & 7, rhg = w >> 3;      // GEMM wave roles

    for (int hh = 0; hh < 2; ++hh) {
        // aggregate 128 nodes of this half into xs (32-lane float2 pattern)
#pragma unroll
        for (int it = 0; it < 4; ++it) {
            int row = it * 32 + g2;          // 0..127 within half
            int dl = hh * 128 + row;
            union { __half2 h2[2]; float2 f2; } u;
            __half2 a0 = __floats2half2_rn(0.f, 0.f), a1 = a0;
            if (fast) {
                int s0 = sst[dl];
                int jend = s0 + hist[dl];
                int j = s0;
                for (; j + 7 < jend; j += 8) {
                    int e0 = elB[j], e1 = elB[j + 1], e2 = elB[j + 2], e3 = elB[j + 3];
                    int e4 = elB[j + 4], e5 = elB[j + 5], e6 = elB[j + 6], e7 = elB[j + 7];
                    float2 r0 = hn[(size_t)e0 * 32 + lane2];
                    float2 r1 = hn[(size_t)e1 * 32 + lane2];
                    float2 r2 = hn[(size_t)e2 * 32 + lane2];
                    float2 r3 = hn[(size_t)e3 * 32 + lane2];
                    float2 r4 = hn[(size_t)e4 * 32 + lane2];
                    float2 r5 = hn[(size_t)e5 * 32 + lane2];
                    float2 r6 = hn[(size_t)e6 * 32 + lane2];
                    float2 r7 = hn[(size_t)e7 * 32 + lane2];
                    const __half2* q0 = (const __half2*)&r0;
                    const __half2* q1 = (const __half2*)&r1;
                    const __half2* q2 = (const __half2*)&r2;
                    const __half2* q3 = (const __half2*)&r3;
                    const __half2* q4 = (const __half2*)&r4;
                    const __half2* q5 = (const __half2*)&r5;
                    const __half2* q6 = (const __half2*)&r6;
                    const __half2* q7 = (const __half2*)&r7;
                    a0 = __hadd2(a0, q0[0]); a1 = __hadd2(a1, q0[1]);
                    a0 = __hadd2(a0, q1[0]); a1 = __hadd2(a1, q1[1]);
                    a0 = __hadd2(a0, q2[0]); a1 = __hadd2(a1, q2[1]);
                    a0 = __hadd2(a0, q3[0]); a1 = __hadd2(a1, q3[1]);
                    a0 = __hadd2(a0, q4[0]); a1 = __hadd2(a1, q4[1]);
                    a0 = __hadd2(a0, q5[0]); a1 = __hadd2(a1, q5[1]);
                    a0 = __hadd2(a0, q6[0]); a1 = __hadd2(a1, q6[1]);
                    a0 = __hadd2(a0, q7[0]); a1 = __hadd2(a1, q7[1]);
                }
                for (; j + 3 < jend; j += 4) {
                    int e0 = elB[j], e1 = elB[j + 1], e2 = elB[j + 2], e3 = elB[j + 3];
                    float2 r0 = hn[(size_t)e0 * 32 + lane2];
                    float2 r1 = hn[(size_t)e1 * 32 + lane2];
                    float2 r2 = hn[(size_t)e2 * 32 + lane2];
                    float2 r3 = hn[(size_t)e3 * 32 + lane2];
                    const __half2* q0 = (const __half2*)&r0;
                    const __half2* q1 = (const __half2*)&r1;
                    const __half2* q2 = (const __half2*)&r2;
                    const __half2* q3 = (const __half2*)&r3;
                    a0 = __hadd2(a0, q0[0]); a1 = __hadd2(a1, q0[1]);
                    a0 = __hadd2(a0, q1[0]); a1 = __hadd2(a1, q1[1]);
                    a0 = __hadd2(a0, q2[0]); a1 = __hadd2(a1, q2[1]);
                    a0 = __hadd2(a0, q3[0]); a1 = __hadd2(a1, q3[1]);
                }
                for (; j < jend; ++j) {
                    float2 r0 = hn[(size_t)elB[j] * 32 + lane2];
                    const __half2* q0 = (const __half2*)&r0;
                    a0 = __hadd2(a0, q0[0]); a1 = __hadd2(a1, q0[1]);
                }
            } else {
                // overflow fallback (statistically never): filter-scan tbuf
                for (int j = ts; j < te; ++j) {
                    unsigned p = tbuf[j];
                    if ((int)(p & (TSZ - 1)) == dl) {
                        float2 r0 = hn[(size_t)(p >> TSH) * 32 + lane2];
                        const __half2* q0 = (const __half2*)&r0;
                        a0 = __hadd2(a0, q0[0]); a1 = __hadd2(a1, q0[1]);
                    }
                }
            }
            float nd = scl[dl];
            float2 f0 = __half22float2(a0), f1 = __half22float2(a1);
            u.h2[0] = __floats2half2_rn(f0.x * nd, f0.y * nd);
            u.h2[1] = __floats2half2_rn(f1.x * nd, f1.y * nd);
            *(float2*)(xs + row * 136 + lane2 * 4) = u.f2;
        }
        __syncthreads();

        // GEMM this 128-row half: wave = (row-half-group rhg, col-tile ct)
        f32x4 acc4[4] = {{0.f, 0.f, 0.f, 0.f}, {0.f, 0.f, 0.f, 0.f},
                         {0.f, 0.f, 0.f, 0.f}, {0.f, 0.f, 0.f, 0.f}};
#pragma unroll
        for (int kk = 0; kk < 4; ++kk) {
            half8_t bf = ((const half8_t*)Wf)[(ct * 4 + kk) * 64 + wl];
#pragma unroll
            for (int rt = 0; rt < 4; ++rt) {
                half8_t af = *(const half8_t*)(xs + (rhg * 64 + rt * 16 + cn) * 136 +
                                               kk * 32 + quad * 8);
                acc4[rt] = __builtin_amdgcn_mfma_f32_16x16x32_f16(af, bf, acc4[rt], 0, 0, 0);
            }
        }
        float bj = b[ct * 16 + cn];
        int node0 = tile * TSZ + hh * 128 + rhg * 64;
#pragma unroll
        for (int rt = 0; rt < 4; ++rt) {
#pragma unroll
            for (int r = 0; r < 4; ++r) {
                int node = node0 + rt * 16 + quad * 4 + r;
                if (node < n)
                    __builtin_nontemporal_store(acc4[rt][r] + bj,
                                                &out[(size_t)node * DIM + ct * 16 + cn]);
            }
        }
        __syncthreads();  // xs reused by next half
    }
}

extern "C" void kernel_launch(void* const* d_in, const int* in_sizes, int n_in,
                              void* d_out, int out_size, void* d_ws, size_t ws_size,
                              hipStream_t stream) {
    const float* h = (const float*)d_in[0];
    const float* W = (const float*)d_in[1];
    const float* b = (const float*)d_in[2];
    const int* esrc = (const int*)d_in[3];
    const int* edst = (const int*)d_in[4];
    float* out = (float*)d_out;

    int n = in_sizes[0] / DIM;   // 100000
    int ne = in_sizes[3];        // 1600000

    int neb = (ne + EBLK - 1) / EBLK;     // 391
    int nt = (n + TSZ - 1) >> TSH;        // 391
    int M = nt * neb;                     // 152881
    int nsc = (M + 1023) / 1024;          // 150

    float2* hn = (float2*)d_ws;                       // n*32 float2 (25.6MB)
    _Float16* Wf = (_Float16*)(hn + (size_t)n * 32);  // 16384 halfs
    int* gh = (int*)(Wf + 16384);                     // M
    int* bsum = gh + ((M + 3) & ~3);                  // 256
    unsigned* tbuf = (unsigned*)(bsum + 256);         // ne

    k1_hist<<<neb + 2, 1024, 0, stream>>>(edst, gh, ne, neb, nt, W, Wf);
    k2_scan<<<nsc, 1024, 0, stream>>>(gh, bsum, M);
    k3_scatter<<<neb, 1024, 0, stream>>>(esrc, edst, gh, bsum, tbuf, ne, neb, M, nt, nsc);
    k4_deg_hn<<<nt, 1024, 0, stream>>>(tbuf, gh, bsum, h, hn, n, ne, neb, nt, nsc);
    k5_tile_gemm<<<nt, 1024, 0, stream>>>(tbuf, gh, bsum, hn, Wf, b, out,
                                          n, ne, neb, nt, nsc);
}

// Round 9
// 202.784 us; speedup vs baseline: 5.9238x; 1.0618x over previous
//
#include <hip/hip_runtime.h>
#include <hip/hip_fp16.h>

#define DIM 128
#define TSH 8
#define TSZ 256    // dst-tile size (sort granularity)
#define QSZ 64     // gather/GEMM quarter-tile (proven gather envelope)
#define EBLK 4096  // edges per hist/scatter block
#define CAPQ 1280  // LDS edge-list cap per quarter (mean ~1023, +8 sigma)

typedef _Float16 half8_t __attribute__((ext_vector_type(8)));
typedef float f32x4 __attribute__((ext_vector_type(4)));
typedef float f32x4v __attribute__((ext_vector_type(4)));

// ws: hn f16[n*128] (25.6MB) | Wf f16[16384] | gh i32[M] | bsum i32[256] |
//     toff i32[nt+1] | tbuf u32[ne]
// Poisons (measured): per-edge global atomics (r5/r7 ~150us); grid.sync (r6
// ~260us/sync). Gather floor: ~70us fabric-bound at 4 blocks/CU TLP (r0/r4);
// fused k5 at 2 blocks/CU paid +15us (r8) -> quarter-tile redesign.

// Blocks [0,neb): LDS histogram of dst-tile key -> gh[key*neb+blk].
// Blocks [neb,neb+2): Wf table:
// Wf[((ct*4+kk)*64+lane)*8+j] = W[ct*16+(lane&15)][kk*32+(lane>>4)*8+j]
__global__ __launch_bounds__(1024) void k1_hist(const int* __restrict__ dst,
                                                int* __restrict__ gh,
                                                int ne, int neb, int nt,
                                                const float* __restrict__ W,
                                                _Float16* __restrict__ Wf) {
    __shared__ int h[512];
    int t = threadIdx.x, blk = blockIdx.x;
    if (blk >= neb) {
        int idx = (blk - neb) * 1024 + t;  // 0..2047
        int ct = idx >> 8, kk = (idx >> 6) & 3, lane = idx & 63;
        int nn = lane & 15, quad = lane >> 4;
        const float* wr = W + (ct * 16 + nn) * DIM + kk * 32 + quad * 8;
        _Float16* o = Wf + (size_t)idx * 8;
#pragma unroll
        for (int j = 0; j < 8; ++j) o[j] = (_Float16)wr[j];
        return;
    }
    if (t < 512) h[t] = 0;
    __syncthreads();
    int e0 = blk * EBLK;
    int e1 = e0 + EBLK; if (e1 > ne) e1 = ne;
    for (int i = e0 + t; i < e1; i += 1024)
        atomicAdd(&h[dst[i] >> TSH], 1);
    __syncthreads();
    for (int k = t; k < nt; k += 1024) gh[k * neb + blk] = h[k];
}

// Exclusive scan of gh in 1024-chunks; bsum[chunk] = raw chunk total.
__global__ __launch_bounds__(1024) void k2_scan(int* __restrict__ g,
                                                int* __restrict__ bsum, int M) {
    __shared__ int wsum[16];
    int t = threadIdx.x, blk = blockIdx.x;
    int base = blk * 1024 + t;
    int v = (base < M) ? g[base] : 0;
    int lane = t & 63, wv = t >> 6;
    int x = v;
#pragma unroll
    for (int off = 1; off < 64; off <<= 1) {
        int y = __shfl_up(x, off, 64);
        if (lane >= off) x += y;
    }
    if (lane == 63) wsum[wv] = x;
    __syncthreads();
    int woff = 0;
    for (int i = 0; i < wv; ++i) woff += wsum[i];
    if (base < M) g[base] = woff + x - v;
    if (t == 0) {
        int s = 0;
#pragma unroll
        for (int i = 0; i < 16; ++i) s += wsum[i];
        bsum[blk] = s;
    }
}

// Blocks [0,neb): LDS-binned scatter to key-sorted tbuf (coalesced; proven).
// Block neb: materialize toff[t] = global start of tile t (kills the bscan
// prologue in k4/k5).
__global__ __launch_bounds__(1024) void k3_scatter(const int* __restrict__ src,
                                                   const int* __restrict__ dst,
                                                   const int* __restrict__ gh,
                                                   const int* __restrict__ bsum,
                                                   unsigned* __restrict__ tbuf,
                                                   int* __restrict__ toff,
                                                   int ne, int neb, int M, int nt,
                                                   int nsc) {
    __shared__ int hD[512];
    __shared__ int ps[256];
    __shared__ int cur[512];
    __shared__ int gbl[256];
    __shared__ unsigned sval[EBLK];        // 16KB
    __shared__ unsigned short skey[EBLK];  // 8KB
    int t = threadIdx.x, blk = blockIdx.x;

    int bd = 0;
    if (t < 256) { bd = (t < nsc) ? bsum[t] : 0; ps[t] = bd; }
    __syncthreads();
    for (int off = 1; off < 256; off <<= 1) {
        int v = (t < 256 && t >= off) ? ps[t - off] : 0;
        __syncthreads();
        if (t < 256) ps[t] += v;
        __syncthreads();
    }
    if (t < 256) gbl[t] = ps[t] - bd;
    __syncthreads();

    if (blk == neb) {
        for (int T = t; T < nt; T += 1024) {
            int idx = T * neb;
            toff[T] = gh[idx] + gbl[idx >> 10];
        }
        if (t == 0) toff[nt] = ne;
        return;
    }

    int p0 = 0, c = 0;
    if (t < 512) {
        if (t < nt) {
            int idx = t * neb + blk;
            p0 = gh[idx] + gbl[idx >> 10];
            int p1 = (idx + 1 < M) ? (gh[idx + 1] + gbl[(idx + 1) >> 10]) : ne;
            c = p1 - p0;
        }
        hD[t] = c;
    }
    __syncthreads();
    int h0 = 0, h1 = 0;
    if (t < 256) { h0 = hD[2 * t]; h1 = hD[2 * t + 1]; ps[t] = h0 + h1; }
    __syncthreads();
    for (int off = 1; off < 256; off <<= 1) {
        int v = (t < 256 && t >= off) ? ps[t - off] : 0;
        __syncthreads();
        if (t < 256) ps[t] += v;
        __syncthreads();
    }
    if (t < 256) {
        int ex0 = ps[t] - h0 - h1;
        cur[2 * t] = ex0;
        cur[2 * t + 1] = ex0 + h0;
    }
    __syncthreads();
    if (t < 512) hD[t] = p0 - cur[t];  // lds-pos p -> global pos hD[k]+p
    __syncthreads();

    int e0 = blk * EBLK;
    int e1 = e0 + EBLK; if (e1 > ne) e1 = ne;
    for (int i = e0 + t; i < e1; i += 1024) {
        int d = dst[i];
        int key = d >> TSH;
        int r = atomicAdd(&cur[key], 1);
        sval[r] = ((unsigned)src[i] << TSH) | (unsigned)(d & (TSZ - 1));
        skey[r] = (unsigned short)key;
    }
    __syncthreads();
    int cnt = e1 - e0;
    for (int p = t; p < cnt; p += 1024)
        tbuf[hD[skey[p]] + p] = sval[p];
}

// One block per tile: exact-dst hist of own tbuf slice -> scl, then pack own
// 256 nodes' hn = f16(h * rsqrt(max(deg,1))). toff-indexed (no scans).
__global__ __launch_bounds__(1024) void k4_deg_hn(const unsigned* __restrict__ tbuf,
                                                  const int* __restrict__ toff,
                                                  const float* __restrict__ hsrc,
                                                  float2* __restrict__ hn,
                                                  int n) {
    __shared__ int hist[TSZ];
    __shared__ float scl[TSZ];
    int t = threadIdx.x, tile = blockIdx.x;
    if (t < 256) hist[t] = 0;
    __syncthreads();
    int ts = toff[tile], te = toff[tile + 1];
    for (int i = ts + t; i < te; i += 1024)
        atomicAdd(&hist[tbuf[i] & (TSZ - 1)], 1);
    __syncthreads();
    if (t < 256) {
        int d = hist[t];
        scl[t] = rsqrtf((float)(d > 1 ? d : 1));
    }
    __syncthreads();
    int qbase = tile * 8192;  // 256 nodes x 32 float4
    for (int q = t; q < 8192; q += 1024) {
        int node = tile * TSZ + (q >> 5);
        if (node < n) {
            f32x4v v = __builtin_nontemporal_load((const f32x4v*)hsrc + qbase + q);
            float sc = scl[q >> 5];
            union { __half2 h2[2]; float2 f2; } u;
            u.h2[0] = __floats2half2_rn(v.x * sc, v.y * sc);
            u.h2[1] = __floats2half2_rn(v.z * sc, v.w * sc);
            hn[qbase + q] = u.f2;
        }
    }
}

// Quarter-tile fused consumer: 512 thr own 64 dst nodes. Re-read own tile's
// tbuf slice (L2-warm via XCD class swizzle), keep own quarter: hist(64) ->
// wave-scan -> rank-scatter into elB -> fabric-bound gather (32-lane float2,
// proven structure) -> MFMA epilogue. LDS ~24KB -> 4 blocks/CU, grid 1568
// (~6 rounds) = the 70us gather envelope.
// Block mapping: c=blk&7 (XCD class), j=blk>>3; tile=c+8*(j>>2), q=j&3 ->
// all 4 quarters of a tile on one XCD, consecutive in dispatch order.
__global__ __launch_bounds__(512) void k5_tile_gemm(
        const unsigned* __restrict__ tbuf, const int* __restrict__ toff,
        const float2* __restrict__ hn, const _Float16* __restrict__ Wf,
        const float* __restrict__ b, float* __restrict__ out,
        int n, int nt) {
    __shared__ int hist[QSZ];
    __shared__ int sst[QSZ];
    __shared__ int cur[QSZ];
    __shared__ float scl[QSZ];
    __shared__ int cntq;
    __shared__ unsigned elB[CAPQ];         // 5KB
    __shared__ _Float16 xs[64 * 136];      // 17.4KB
    int t = threadIdx.x;
    int c = blockIdx.x & 7, j = blockIdx.x >> 3;
    int tile = c + 8 * (j >> 2), q = j & 3;
    if (tile >= nt) return;

    int ts = toff[tile], te = toff[tile + 1];
    if (t < QSZ) hist[t] = 0;
    __syncthreads();
    // pass 1: histogram own quarter's dst-locals
    for (int i = ts + t; i < te; i += 512) {
        unsigned p = tbuf[i];
        int dl = (int)(p & (TSZ - 1));
        if ((dl >> 6) == q) atomicAdd(&hist[dl & (QSZ - 1)], 1);
    }
    __syncthreads();
    if (t < QSZ) {
        int d = hist[t];
        int x = d;
#pragma unroll
        for (int off = 1; off < 64; off <<= 1) {
            int y = __shfl_up(x, off, 64);
            if (t >= off) x += y;
        }
        sst[t] = x - d;
        cur[t] = x - d;
        scl[t] = rsqrtf((float)(d > 1 ? d : 1));
        if (t == QSZ - 1) cntq = x;
    }
    __syncthreads();
    bool fast = (cntq <= CAPQ);
    if (fast) {
        // pass 2: rank-scatter own quarter into dst-sorted LDS list
        for (int i = ts + t; i < te; i += 512) {
            unsigned p = tbuf[i];
            int dl = (int)(p & (TSZ - 1));
            if ((dl >> 6) == q) {
                int r = atomicAdd(&cur[dl & (QSZ - 1)], 1);
                elB[r] = p >> TSH;  // src node
            }
        }
        __syncthreads();
    }

    int g2 = t >> 5, lane2 = t & 31;  // 16 groups x 32 lanes
#pragma unroll
    for (int it = 0; it < 4; ++it) {
        int row = it * 16 + g2;       // 0..63 (local node)
        union { __half2 h2[2]; float2 f2; } u;
        __half2 a0 = __floats2half2_rn(0.f, 0.f), a1 = a0;
        if (fast) {
            int s0 = sst[row];
            int jend = s0 + hist[row];
            int jj = s0;
            for (; jj + 7 < jend; jj += 8) {
                int e0 = elB[jj], e1 = elB[jj + 1], e2 = elB[jj + 2], e3 = elB[jj + 3];
                int e4 = elB[jj + 4], e5 = elB[jj + 5], e6 = elB[jj + 6], e7 = elB[jj + 7];
                float2 r0 = hn[(size_t)e0 * 32 + lane2];
                float2 r1 = hn[(size_t)e1 * 32 + lane2];
                float2 r2 = hn[(size_t)e2 * 32 + lane2];
                float2 r3 = hn[(size_t)e3 * 32 + lane2];
                float2 r4 = hn[(size_t)e4 * 32 + lane2];
                float2 r5 = hn[(size_t)e5 * 32 + lane2];
                float2 r6 = hn[(size_t)e6 * 32 + lane2];
                float2 r7 = hn[(size_t)e7 * 32 + lane2];
                const __half2* q0 = (const __half2*)&r0;
                const __half2* q1 = (const __half2*)&r1;
                const __half2* q2 = (const __half2*)&r2;
                const __half2* q3 = (const __half2*)&r3;
                const __half2* q4 = (const __half2*)&r4;
                const __half2* q5 = (const __half2*)&r5;
                const __half2* q6 = (const __half2*)&r6;
                const __half2* q7 = (const __half2*)&r7;
                a0 = __hadd2(a0, q0[0]); a1 = __hadd2(a1, q0[1]);
                a0 = __hadd2(a0, q1[0]); a1 = __hadd2(a1, q1[1]);
                a0 = __hadd2(a0, q2[0]); a1 = __hadd2(a1, q2[1]);
                a0 = __hadd2(a0, q3[0]); a1 = __hadd2(a1, q3[1]);
                a0 = __hadd2(a0, q4[0]); a1 = __hadd2(a1, q4[1]);
                a0 = __hadd2(a0, q5[0]); a1 = __hadd2(a1, q5[1]);
                a0 = __hadd2(a0, q6[0]); a1 = __hadd2(a1, q6[1]);
                a0 = __hadd2(a0, q7[0]); a1 = __hadd2(a1, q7[1]);
            }
            for (; jj + 3 < jend; jj += 4) {
                int e0 = elB[jj], e1 = elB[jj + 1], e2 = elB[jj + 2], e3 = elB[jj + 3];
                float2 r0 = hn[(size_t)e0 * 32 + lane2];
                float2 r1 = hn[(size_t)e1 * 32 + lane2];
                float2 r2 = hn[(size_t)e2 * 32 + lane2];
                float2 r3 = hn[(size_t)e3 * 32 + lane2];
                const __half2* q0 = (const __half2*)&r0;
                const __half2* q1 = (const __half2*)&r1;
                const __half2* q2 = (const __half2*)&r2;
                const __half2* q3 = (const __half2*)&r3;
                a0 = __hadd2(a0, q0[0]); a1 = __hadd2(a1, q0[1]);
                a0 = __hadd2(a0, q1[0]); a1 = __hadd2(a1, q1[1]);
                a0 = __hadd2(a0, q2[0]); a1 = __hadd2(a1, q2[1]);
                a0 = __hadd2(a0, q3[0]); a1 = __hadd2(a1, q3[1]);
            }
            for (; jj < jend; ++jj) {
                float2 r0 = hn[(size_t)elB[jj] * 32 + lane2];
                const __half2* q0 = (const __half2*)&r0;
                a0 = __hadd2(a0, q0[0]); a1 = __hadd2(a1, q0[1]);
            }
        } else {
            // overflow fallback (statistically never): filter-scan the slice
            int want = (q << 6) | row;
            for (int i = ts; i < te; ++i) {
                unsigned p = tbuf[i];
                if ((int)(p & (TSZ - 1)) == want) {
                    float2 r0 = hn[(size_t)(p >> TSH) * 32 + lane2];
                    const __half2* q0 = (const __half2*)&r0;
                    a0 = __hadd2(a0, q0[0]); a1 = __hadd2(a1, q0[1]);
                }
            }
        }
        float nd = scl[row];
        float2 f0 = __half22float2(a0), f1 = __half22float2(a1);
        u.h2[0] = __floats2half2_rn(f0.x * nd, f0.y * nd);
        u.h2[1] = __floats2half2_rn(f1.x * nd, f1.y * nd);
        *(float2*)(xs + row * 136 + lane2 * 4) = u.f2;
    }
    __syncthreads();

    // GEMM 64 rows: 8 waves; wave w = col-tile; 4 row-tiles x 4 chained MFMA
    int w = t >> 6, wl = t & 63, cn = wl & 15, quad = wl >> 4;
    f32x4 acc4[4] = {{0.f, 0.f, 0.f, 0.f}, {0.f, 0.f, 0.f, 0.f},
                     {0.f, 0.f, 0.f, 0.f}, {0.f, 0.f, 0.f, 0.f}};
#pragma unroll
    for (int kk = 0; kk < 4; ++kk) {
        half8_t bf = ((const half8_t*)Wf)[(w * 4 + kk) * 64 + wl];
#pragma unroll
        for (int rt = 0; rt < 4; ++rt) {
            half8_t af = *(const half8_t*)(xs + (rt * 16 + cn) * 136 + kk * 32 + quad * 8);
            acc4[rt] = __builtin_amdgcn_mfma_f32_16x16x32_f16(af, bf, acc4[rt], 0, 0, 0);
        }
    }
    float bj = b[w * 16 + cn];
    int node0 = tile * TSZ + q * QSZ;
#pragma unroll
    for (int rt = 0; rt < 4; ++rt) {
#pragma unroll
        for (int r = 0; r < 4; ++r) {
            int node = node0 + rt * 16 + quad * 4 + r;
            if (node < n)
                __builtin_nontemporal_store(acc4[rt][r] + bj,
                                            &out[(size_t)node * DIM + w * 16 + cn]);
        }
    }
}

extern "C" void kernel_launch(void* const* d_in, const int* in_sizes, int n_in,
                              void* d_out, int out_size, void* d_ws, size_t ws_size,
                              hipStream_t stream) {
    const float* h = (const float*)d_in[0];
    const float* W = (const float*)d_in[1];
    const float* b = (const float*)d_in[2];
    const int* esrc = (const int*)d_in[3];
    const int* edst = (const int*)d_in[4];
    float* out = (float*)d_out;

    int n = in_sizes[0] / DIM;   // 100000
    int ne = in_sizes[3];        // 1600000

    int neb = (ne + EBLK - 1) / EBLK;     // 391
    int nt = (n + TSZ - 1) >> TSH;        // 391
    int M = nt * neb;                     // 152881
    int nsc = (M + 1023) / 1024;          // 150

    float2* hn = (float2*)d_ws;                       // n*32 float2 (25.6MB)
    _Float16* Wf = (_Float16*)(hn + (size_t)n * 32);  // 16384 halfs
    int* gh = (int*)(Wf + 16384);                     // M
    int* bsum = gh + ((M + 3) & ~3);                  // 256
    int* toff = bsum + 256;                           // nt+1
    unsigned* tbuf = (unsigned*)(toff + ((nt + 5) & ~3));  // ne

    k1_hist<<<neb + 2, 1024, 0, stream>>>(edst, gh, ne, neb, nt, W, Wf);
    k2_scan<<<nsc, 1024, 0, stream>>>(gh, bsum, M);
    k3_scatter<<<neb + 1, 1024, 0, stream>>>(esrc, edst, gh, bsum, tbuf, toff,
                                             ne, neb, M, nt, nsc);
    k4_deg_hn<<<nt, 1024, 0, stream>>>(tbuf, toff, h, hn, n);
    int P = ((nt + 7) / 8) * 4;           // quarter-slots per XCD class (196)
    k5_tile_gemm<<<8 * P, 512, 0, stream>>>(tbuf, toff, hn, Wf, b, out, n, nt);
}